// Round 1
// baseline (205.102 us; speedup 1.0000x reference)
//
#include <hip/hip_runtime.h>
#include <cmath>

// ---------------------------------------------------------------------------
// NeuralField: hashgrid encode (8 levels x 8 feats, smoothstep) + MLP
// 64 -> 256 -> 256 -> 256 -> 1 (ReLU x3, linear out), N = 262144 points.
// Strategy: fully fused per-64-point-tile kernel. Encode -> LDS (bf16),
// three bf16 MFMA layers (fp32 accum) ping-ponging between two 32 KB LDS
// buffers (XOR-swizzled to kill bank conflicts), final 256->1 dot with
// shuffle reduce. Weights pre-packed to bf16 in d_ws each launch.
// ---------------------------------------------------------------------------

#define N_LEVELS 8
#define TABLE_PAD 8192
#define TILE_M 64
#define LSTRIDE 256          // shorts per LDS row (no pad; XOR swizzle instead)

typedef __attribute__((ext_vector_type(8))) short short8;
typedef __attribute__((ext_vector_type(4))) float float4v;

struct LevelParams {
  float scale[N_LEVELS];
  int   res[N_LEVELS];
  int   size[N_LEVELS];
};

__device__ __forceinline__ unsigned short f2bf(float f) {
  unsigned int u = __float_as_uint(f);
  u += 0x7fffu + ((u >> 16) & 1u);      // round to nearest even
  return (unsigned short)(u >> 16);
}
__device__ __forceinline__ float bf2f(unsigned short h) {
  return __uint_as_float(((unsigned int)h) << 16);
}

// Pack W (K x 256 row-major f32) -> bf16 [kb][n][ki] so one wave's B-fragment
// (16 cols x 32 k) is a contiguous, fully-coalesced 1 KB chunk.
// Wp layout: [W0p: 2*256*32][W1p: 8*256*32][W2p: 8*256*32]
__global__ void pack_weights_kernel(const float* __restrict__ W0,
                                    const float* __restrict__ W1,
                                    const float* __restrict__ W2,
                                    unsigned short* __restrict__ Wp) {
  int tid = blockIdx.x * blockDim.x + threadIdx.x;
  const float* src;
  int base, e;
  if (tid < 16384)        { src = W0; base = 0;     e = tid;         }
  else if (tid < 81920)   { src = W1; base = 16384; e = tid - 16384; }
  else if (tid < 147456)  { src = W2; base = 81920; e = tid - 81920; }
  else return;
  int ki = e & 31;
  int n  = (e >> 5) & 255;
  int kb = e >> 13;
  Wp[base + e] = f2bf(src[(kb * 32 + ki) * 256 + n]);
}

__global__ __launch_bounds__(256, 2) void neural_field_kernel(
    const float* __restrict__ x,
    const float* __restrict__ table,
    const unsigned short* __restrict__ Wp,
    const float* __restrict__ W3,
    float* __restrict__ out,
    LevelParams P) {
  // Two ping-pong activation buffers, 64 rows x 256 bf16, 32 KB each.
  // Element (row, col) lives at row*256 + (chunk ^ (row & 15))*8 + (col & 7)
  // where chunk = col >> 3.  16 B-granular XOR swizzle -> A-fragment
  // ds_read_b128s are 2-way-conflict-free (free on CDNA4).
  __shared__ unsigned short buf0[TILE_M * LSTRIDE];
  __shared__ unsigned short buf1[TILE_M * LSTRIDE];

  const int t  = threadIdx.x;
  const int g0 = blockIdx.x * TILE_M;

  // ---------------- Phase 1: hashgrid encode -> buf0 cols [0,64) -----------
  {
    int p  = t & 63;       // point within tile
    int lg = t >> 6;       // wave id -> handles levels 2lg, 2lg+1
    float2 xy = ((const float2*)x)[g0 + p];
    for (int li = 0; li < 2; ++li) {
      int l = lg * 2 + li;
      float scale = P.scale[l];
      int res = P.res[l], size = P.size[l];
      float posx = xy.x * scale + 0.5f;
      float posy = xy.y * scale + 0.5f;
      float pgx = floorf(posx), pgy = floorf(posy);
      float fx = posx - pgx, fy = posy - pgy;
      float wx = fx * fx * (3.0f - 2.0f * fx);
      float wy = fy * fy * (3.0f - 2.0f * fy);
      int px = (int)pgx, py = (int)pgy;
      float acc[8] = {0, 0, 0, 0, 0, 0, 0, 0};
      for (int dy = 0; dy < 2; ++dy) {
        float wyv = dy ? wy : 1.0f - wy;
        for (int dx = 0; dx < 2; ++dx) {
          float wgt = (dx ? wx : 1.0f - wx) * wyv;
          int idx = (px + dx) + (py + dy) * res;
          if (idx >= size) idx -= size;   // idx < 2*size always
          const float4* tp =
              (const float4*)(table + ((size_t)l * TABLE_PAD + idx) * 8);
          float4 t0 = tp[0], t1 = tp[1];
          acc[0] += wgt * t0.x; acc[1] += wgt * t0.y;
          acc[2] += wgt * t0.z; acc[3] += wgt * t0.w;
          acc[4] += wgt * t1.x; acc[5] += wgt * t1.y;
          acc[6] += wgt * t1.z; acc[7] += wgt * t1.w;
        }
      }
      union { unsigned short s[8]; short8 v; } u;
      for (int j = 0; j < 8; ++j) u.s[j] = f2bf(acc[j]);
      int pos = (l ^ (p & 15)) * 8;       // chunk l, swizzled
      *(short8*)&buf0[p * LSTRIDE + pos] = u.v;
    }
  }

  const int lane  = t & 63;
  const int w     = t >> 6;
  const int l15   = lane & 15;
  const int quad  = lane >> 4;
  const int wbase = w * 64;     // this wave's 64 output columns

  // ---------------- MFMA layer: [64 x K] @ [K x 256] + ReLU ----------------
  auto run_layer = [&](const unsigned short* inb, unsigned short* outb,
                       const unsigned short* Wpl, int K) {
    float4v acc[4][4];
    for (int mt = 0; mt < 4; ++mt)
      for (int nt = 0; nt < 4; ++nt)
        acc[mt][nt] = (float4v){0.f, 0.f, 0.f, 0.f};

    for (int kb = 0; kb < K / 32; ++kb) {
      short8 a[4], b[4];
      for (int mt = 0; mt < 4; ++mt) {
        int row = mt * 16 + l15;
        int kchunk = kb * 4 + quad;               // 8 bf16 per chunk
        int pos = (kchunk ^ l15) * 8;             // row&15 == l15 here
        a[mt] = *(const short8*)&inb[row * LSTRIDE + pos];
      }
      for (int nt = 0; nt < 4; ++nt) {
        int n = wbase + nt * 16 + l15;
        b[nt] = *(const short8*)&Wpl[(kb * 256 + n) * 32 + quad * 8];
      }
      for (int mt = 0; mt < 4; ++mt)
        for (int nt = 0; nt < 4; ++nt)
          acc[mt][nt] = __builtin_amdgcn_mfma_f32_16x16x32_bf16(
              a[mt], b[nt], acc[mt][nt], 0, 0, 0);
    }

    // Epilogue: ReLU, cvt bf16, store C (col = lane&15, row = quad*4+reg)
    for (int mt = 0; mt < 4; ++mt) {
      for (int nt = 0; nt < 4; ++nt) {
        int col = wbase + nt * 16 + l15;
        int chunk = col >> 3, within = col & 7;
        for (int r = 0; r < 4; ++r) {
          int row = mt * 16 + quad * 4 + r;
          float v = acc[mt][nt][r];
          v = v > 0.f ? v : 0.f;
          int pos = (chunk ^ (row & 15)) * 8 + within;
          outb[row * LSTRIDE + pos] = f2bf(v);
        }
      }
    }
  };

  __syncthreads();
  run_layer(buf0, buf1, Wp,         64);   // layer 0: enc(64) -> h0
  __syncthreads();
  run_layer(buf1, buf0, Wp + 16384, 256);  // layer 1
  __syncthreads();
  run_layer(buf0, buf1, Wp + 81920, 256);  // layer 2
  __syncthreads();

  // ---------------- Final layer: out[p] = h2[p] . W3 -----------------------
  {
    int p = t >> 2;          // point within tile
    int q = t & 3;           // quarter of K=256
    float s = 0.f;
    for (int c8 = 0; c8 < 8; ++c8) {
      int chunk = q * 8 + c8;
      int pos = (chunk ^ (p & 15)) * 8;
      const unsigned short* h = &buf1[p * LSTRIDE + pos];
      const float* w3 = W3 + chunk * 8;
      for (int j = 0; j < 8; ++j) s += bf2f(h[j]) * w3[j];
    }
    s += __shfl_xor(s, 1);
    s += __shfl_xor(s, 2);
    if (q == 0) out[g0 + p] = s;
  }
}

extern "C" void kernel_launch(void* const* d_in, const int* in_sizes, int n_in,
                              void* d_out, int out_size, void* d_ws,
                              size_t ws_size, hipStream_t stream) {
  const float* x     = (const float*)d_in[0];
  const float* table = (const float*)d_in[1];
  const float* W0    = (const float*)d_in[2];
  const float* W1    = (const float*)d_in[3];
  const float* W2    = (const float*)d_in[4];
  const float* W3    = (const float*)d_in[5];
  float* out = (float*)d_out;
  int N = in_sizes[0] / 2;

  unsigned short* Wp = (unsigned short*)d_ws;   // 147456 bf16 = 288 KB

  // Level params, double precision to match the Python reference exactly.
  LevelParams P;
  const double c = 1.2599210739135742;
  double m = 1.0;
  for (int l = 0; l < N_LEVELS; ++l) {
    double scale_d = 16.0 * m - 1.0;
    int res = (int)std::ceil(scale_d) + 1;
    long long sz = ((long long)res * res + 7) / 8 * 8;
    if (sz > (1LL << 19)) sz = 1LL << 19;
    P.scale[l] = (float)scale_d;
    P.res[l]   = res;
    P.size[l]  = (int)sz;
    m *= c;
  }

  hipLaunchKernelGGL(pack_weights_kernel, dim3(576), dim3(256), 0, stream,
                     W0, W1, W2, Wp);
  hipLaunchKernelGGL(neural_field_kernel, dim3(N / TILE_M), dim3(256), 0,
                     stream, x, table, Wp, W3, out, P);
}